// Round 19
// baseline (215.030 us; speedup 1.0000x reference)
//
#include <hip/hip_runtime.h>

// DART_Net fused kernel, MI355X (gfx950). Round 19.
// B=64, N=128, M=64, LH=LO=128. Output [B*N] fp32.
//
// R19 = R14 (152.2us champion) with B-fragments moved from LDS to a
// pre-converted GLOBAL image (prep kernel -> d_ws, 128 KB, L2/L3-resident).
// Rationale: wall 172 @ VALUBusy 51% = half the time is unhidden latency at
// 4 waves/SIMD, and residency was pinned by the 32KB sBf making LDS/block
// 39.9KB -> exactly 4 blocks/CU. Dropping sBf: LDS 10.3KB -> occupancy cap
// 32 waves/CU (VGPR-64 bound). B-frag reads become coalesced 1KB-per-wave
// global_load_dwordx4 from a 128KB image (L2 budget ~786MB/dispatch ~ 23us
// at 34.5TB/s, overlapped). Everything else R14 verbatim.
// Fallback: if ws_size < 128KB, launch the exact R14 kernel (host-side
// constant branch, graph-safe).

typedef __attribute__((ext_vector_type(8))) short short8;   // bf16x8 frag
typedef __attribute__((ext_vector_type(4))) float f32x4;
typedef __attribute__((ext_vector_type(4))) unsigned uint4v;

#define G_ 8
#define NATOMS (64 * 128)
#define SCL   14.42695040888963f     // 10/ln2
#define SCL01 1.442695040888963f     // 0.1 * SCL
#define INVS  0.06931471805599453f   // ln2/10
#define WS_BF_BYTES (4 * 32 * 64 * 16)   // 4 species x 32 frags x 64 lanes x 16B

struct DartParams {
  const float* x[4];    // aj, ak, al, ai
  const float* W1[4];
  const float* b1[4];
  const float* W2[4];
  const float* b2[4];
  const float* HW[4];   // 64x128, 32x64, 16x32, 1x16
  const float* Hb[4];
  const short8* gBf;    // [4][32][64] bf16 B-frags (prep output), or null
  float* out;
};

__device__ __forceinline__ float celu01(float z) {
  float t = fmaf(0.1f, __builtin_amdgcn_exp2f(z * SCL), -0.1f);
  return __builtin_amdgcn_fmed3f(z, t, 0.0f);
}
__device__ __forceinline__ float celu_s(float zs) {
  // scaled domain: zs = S*z; returns S*celu(z). 3 VALU ops.
  float t = fmaf(SCL01, __builtin_amdgcn_exp2f(zs), -SCL01);
  return __builtin_amdgcn_fmed3f(zs, t, 0.0f);
}
__device__ __forceinline__ unsigned cvtpk(float a, float b) {
  unsigned r;
  asm("v_cvt_pk_bf16_f32 %0, %1, %2" : "=v"(r) : "v"(a), "v"(b));
  return r;
}
__device__ __forceinline__ short8 pack4(unsigned a, unsigned b, unsigned c, unsigned d) {
  uint4v u = {a, b, c, d};
  return __builtin_bit_cast(short8, u);
}

// ---------------- prep: W2 f32 -> bf16 MFMA B-frag image in ws ----------------
extern "C" __global__ __launch_bounds__(256)
void dart_prep(const float* W2j, const float* W2k, const float* W2l,
               const float* W2i, short8* ws) {
  const int s = (int)blockIdx.x;            // 0..3 species (j,k,l,i)
  const float* W2 = (s == 0) ? W2j : (s == 1) ? W2k : (s == 2) ? W2l : W2i;
  const int t = threadIdx.x;
  const int lane = t & 63, wave = t >> 6;
  const int lq = lane >> 4, lr = lane & 15;
#pragma unroll
  for (int ff = 0; ff < 8; ++ff) {
    const int f  = wave * 8 + ff;
    const int ob = f >> 2, kb = f & 3;
    const f32x4* src = (const f32x4*)(W2 + (ob * 16 + lr) * 128 + kb * 32 + lq * 8);
    f32x4 lo = src[0], hi = src[1];
    ws[(s * 32 + f) * 64 + lane] = pack4(cvtpk(lo.x, lo.y), cvtpk(lo.z, lo.w),
                                         cvtpk(hi.x, hi.y), cvtpk(hi.z, hi.w));
  }
}

// ---------------- main kernel, global B-frags, small LDS ----------------
// LDS layout (bytes): sW1 @0 (2304 = 144*16), sB2 @2304 (512), sAtm @2816
// (4096), sIm @6912 (32), sH1 @6944 (2048), sH2 @8992 (1024), sH3 @10016
// (512) -> 10528 total.
#define LDSG_BYTES 10528

__device__ __forceinline__ void stage_w1(
    const float* W1g, const float* b1g, const float* b2g,
    f32x4* sW1v, float* sB2v, int t) {
  __syncthreads();
  if (t < 128) {
    const float* w = W1g + t * 3;
    f32x4 v;
    v.x = w[0] * SCL; v.y = w[1] * SCL; v.z = w[2] * SCL; v.w = b1g[t] * SCL;
    sW1v[t + (t >> 3)] = v;
    sB2v[t] = b2g[t] * SCL;
  }
  __syncthreads();
}

extern "C" __global__ __launch_bounds__(256, 4)
void dart_fused_g(DartParams p) {
  __shared__ __align__(16) char lds[LDSG_BYTES];
  f32x4*  sW1v = (f32x4*)lds;
  float*  sB2v = (float*)(lds + 2304);
  float*  sAtm = (float*)(lds + 2816);    // [8*128]
  float*  sIm  = (float*)(lds + 6912);    // [8]
  float*  sH1  = (float*)(lds + 6944);    // [8*64]
  float*  sH2  = (float*)(lds + 8992);    // [8*32]
  float*  sH3  = (float*)(lds + 10016);   // [8*16]

  const int t    = threadIdx.x;
  const int lane = t & 63;
  const int wave = t >> 6;        // 0..3 -> row block wave*16
  const int lq   = lane >> 4;
  const int lr   = lane & 15;
  const int atom0 = (int)blockIdx.x * G_;

  for (int i = t; i < G_ * 128; i += 256) sAtm[i] = 0.0f;

  // ---------------- species j, k, l ----------------
#pragma unroll 1
  for (int s = 0; s < 3; ++s) {
    stage_w1(p.W1[s], p.b1[s], p.b2[s], sW1v, sB2v, t);
    const short8* gB = p.gBf + (s * 32) * 64 + lane;

    const float* X = p.x[s];
    const int rowoff = wave * 16 + lr;

#pragma unroll 1
    for (int qq = 0; qq < 2; ++qq) {
      const int gq = qq * 4;
      float x0[4], x1[4], x2[4];
#pragma unroll
      for (int a = 0; a < 4; ++a) {
        const float* xp = X + ((atom0 + gq + a) * 64 + rowoff) * 3;
        x0[a] = xp[0]; x1[a] = xp[1]; x2[a] = xp[2];
      }
      float mr[4][4];
#pragma unroll
      for (int a = 0; a < 4; ++a) {
        const unsigned mw = (unsigned)__ballot((x0[a] + x1[a] + x2[a]) != 0.0f);
#pragma unroll
        for (int j = 0; j < 4; ++j)
          mr[a][j] = ((mw >> (lq * 4 + j)) & 1u) ? INVS : 0.0f;
      }

      // ---- layer 1 (scaled) + celu_s + cvt_pk pack, 4 atoms ----
      short8 af[4][4];   // [atom][kb]
#pragma unroll
      for (int kb = 0; kb < 4; ++kb) {
        const f32x4* wrow = sW1v + kb * 36 + lq * 9;
        unsigned u[4][4];
#pragma unroll
        for (int e2 = 0; e2 < 4; ++e2) {
          f32x4 wA = wrow[2 * e2], wB = wrow[2 * e2 + 1];
#pragma unroll
          for (int a = 0; a < 4; ++a) {
            float zA = celu_s(fmaf(x0[a], wA.x, fmaf(x1[a], wA.y, fmaf(x2[a], wA.z, wA.w))));
            float zB = celu_s(fmaf(x0[a], wB.x, fmaf(x1[a], wB.y, fmaf(x2[a], wB.z, wB.w))));
            u[a][e2] = cvtpk(zA, zB);
          }
        }
#pragma unroll
        for (int a = 0; a < 4; ++a)
          af[a][kb] = pack4(u[a][0], u[a][1], u[a][2], u[a][3]);
      }

      // ---- per-ob: one global B-frag read feeds 4 atoms; 16 MFMAs ----
#pragma unroll
      for (int ob = 0; ob < 8; ++ob) {
        const short8* fb = gB + (ob * 4) * 64;
        const float bv = sB2v[ob * 16 + lr];   // S*b2 -> acc is z2'
        f32x4 ac[4];
#pragma unroll
        for (int a = 0; a < 4; ++a) ac[a] = {bv, bv, bv, bv};
#pragma unroll
        for (int kb = 0; kb < 4; ++kb) {
          short8 fr = fb[kb * 64];
#pragma unroll
          for (int a = 0; a < 4; ++a)
            ac[a] = __builtin_amdgcn_mfma_f32_16x16x32_bf16(af[a][kb], fr, ac[a], 0, 0, 0);
        }
        const int col = ob * 16 + lr;
#pragma unroll
        for (int a = 0; a < 4; ++a) {
          float pa = 0.0f;
#pragma unroll
          for (int j = 0; j < 4; ++j)
            pa = fmaf(celu_s(ac[a][j]), mr[a][j], pa);   // mr carries 1/S
          pa += __shfl_xor(pa, 16, 64);
          pa += __shfl_xor(pa, 32, 64);
          if (lane < 16) atomicAdd(&sAtm[(gq + a) * 128 + col], pa);
        }
      }
    }
  }

  // ---------------- species i ----------------
  {
    stage_w1(p.W1[3], p.b1[3], p.b2[3], sW1v, sB2v, t);
    const short8* gB = p.gBf + (3 * 32) * 64 + lane;

    const int ri = min(atom0 + lr, NATOMS - 1);
    const float* xp = p.x[3] + ri * 3;
    const float x0 = xp[0], x1 = xp[1], x2 = xp[2];
    const unsigned mbi = (unsigned)__ballot((x0 + x1 + x2) != 0.0f);

    short8 af[4];
#pragma unroll
    for (int kb = 0; kb < 4; ++kb) {
      const f32x4* wrow = sW1v + kb * 36 + lq * 9;
      unsigned u[4];
#pragma unroll
      for (int e2 = 0; e2 < 4; ++e2) {
        f32x4 wA = wrow[2 * e2], wB = wrow[2 * e2 + 1];
        float cA = celu_s(fmaf(x0, wA.x, fmaf(x1, wA.y, fmaf(x2, wA.z, wA.w))));
        float cB = celu_s(fmaf(x0, wB.x, fmaf(x1, wB.y, fmaf(x2, wB.z, wB.w))));
        u[e2] = cvtpk(cA, cB);
      }
      af[kb] = pack4(u[0], u[1], u[2], u[3]);
    }
#pragma unroll
    for (int oo = 0; oo < 2; ++oo) {
      const int ob = wave * 2 + oo;
      const int col = ob * 16 + lr;
      const float bv = sB2v[col];
      const short8* fb = gB + (ob * 4) * 64;
      f32x4 a = {bv, bv, bv, bv};
#pragma unroll
      for (int kb = 0; kb < 4; ++kb)
        a = __builtin_amdgcn_mfma_f32_16x16x32_bf16(af[kb], fb[kb * 64], a, 0, 0, 0);
#pragma unroll
      for (int j = 0; j < 4; ++j) {
        const int g = lq * 4 + j;
        if (g < G_) {
          float m = ((mbi >> g) & 1u) ? INVS : 0.0f;
          sAtm[g * 128 + col] += celu_s(a[j]) * m;
        }
      }
    }
    if (wave == 0 && t < G_) sIm[t] = (float)((mbi >> t) & 1u);
    __syncthreads();
  }

  // ---------------- head MLP (R14 original: 128 threads x 4) ----------------
  {
    const int g = t >> 4, u = t & 15;
    const bool act = (g < G_);
    if (act) {
      const f32x4* atm4 = (const f32x4*)(sAtm + g * 128);
#pragma unroll
      for (int rep = 0; rep < 4; ++rep) {
        const int o = rep * 16 + u;
        const f32x4* w4 = (const f32x4*)(p.HW[0] + o * 128);
        float z = p.Hb[0][o];
#pragma unroll 8
        for (int c = 0; c < 32; ++c) {
          f32x4 a = atm4[c], w = w4[c];
          z = fmaf(a.x, w.x, fmaf(a.y, w.y, fmaf(a.z, w.z, fmaf(a.w, w.w, z))));
        }
        sH1[g * 64 + o] = celu01(z);
      }
    }
    __syncthreads();
    if (act) {
      const f32x4* h14 = (const f32x4*)(sH1 + g * 64);
#pragma unroll
      for (int rep = 0; rep < 2; ++rep) {
        const int o = rep * 16 + u;
        const f32x4* w4 = (const f32x4*)(p.HW[1] + o * 64);
        float z = p.Hb[1][o];
#pragma unroll
        for (int c = 0; c < 16; ++c) {
          f32x4 a = h14[c], w = w4[c];
          z = fmaf(a.x, w.x, fmaf(a.y, w.y, fmaf(a.z, w.z, fmaf(a.w, w.w, z))));
        }
        sH2[g * 32 + o] = celu01(z);
      }
    }
    __syncthreads();
    if (act) {
      const f32x4* h24 = (const f32x4*)(sH2 + g * 32);
      const f32x4* w4 = (const f32x4*)(p.HW[2] + u * 32);
      float z = p.Hb[2][u];
#pragma unroll
      for (int c = 0; c < 8; ++c) {
        f32x4 a = h24[c], w = w4[c];
        z = fmaf(a.x, w.x, fmaf(a.y, w.y, fmaf(a.z, w.z, fmaf(a.w, w.w, z))));
      }
      sH3[g * 16 + u] = celu01(z);
    }
    __syncthreads();
    if (act && u == 0) {
      const f32x4* h34 = (const f32x4*)(sH3 + g * 16);
      const f32x4* w4 = (const f32x4*)p.HW[3];
      float z = p.Hb[3][0];
#pragma unroll
      for (int c = 0; c < 4; ++c) {
        f32x4 a = h34[c], w = w4[c];
        z = fmaf(a.x, w.x, fmaf(a.y, w.y, fmaf(a.z, w.z, fmaf(a.w, w.w, z))));
      }
      p.out[atom0 + g] = z * sIm[g];
    }
  }
}

// ---------------- fallback: R14 kernel verbatim (LDS B-frags) ----------------
#define LDS_BYTES 39712

__device__ __forceinline__ void stage_species_l(
    const float* W1g, const float* b1g, const float* W2g, const float* b2g,
    f32x4* sW1v, float* sB2v, short8* sBfv,
    int t, int lane, int lq, int lr, int wave) {
  __syncthreads();
  if (t < 128) {
    const float* w = W1g + t * 3;
    f32x4 v;
    v.x = w[0] * SCL; v.y = w[1] * SCL; v.z = w[2] * SCL; v.w = b1g[t] * SCL;
    sW1v[t + (t >> 3)] = v;
    sB2v[t] = b2g[t] * SCL;
  }
#pragma unroll
  for (int ff = 0; ff < 8; ++ff) {
    const int f  = wave * 8 + ff;
    const int ob = f >> 2, kb = f & 3;
    const f32x4* src = (const f32x4*)(W2g + (ob * 16 + lr) * 128 + kb * 32 + lq * 8);
    f32x4 lo = src[0], hi = src[1];
    sBfv[f * 64 + lane] = pack4(cvtpk(lo.x, lo.y), cvtpk(lo.z, lo.w),
                                cvtpk(hi.x, hi.y), cvtpk(hi.z, hi.w));
  }
  __syncthreads();
}

extern "C" __global__ __launch_bounds__(256, 4)
void dart_fused_l(DartParams p) {
  __shared__ __align__(16) char lds[LDS_BYTES];
  short8* sBfv = (short8*)lds;
  f32x4*  sW1v = (f32x4*)(lds + 32768);
  float*  sB2v = (float*)(lds + 35072);
  float*  sAtm = (float*)(lds + 35584);
  float*  sIm  = (float*)(lds + 39680);
  float*  sH1  = (float*)lds;
  float*  sH2  = (float*)(lds + 2048);
  float*  sH3  = (float*)(lds + 3072);

  const int t    = threadIdx.x;
  const int lane = t & 63;
  const int wave = t >> 6;
  const int lq   = lane >> 4;
  const int lr   = lane & 15;
  const int atom0 = (int)blockIdx.x * G_;

  for (int i = t; i < G_ * 128; i += 256) sAtm[i] = 0.0f;

#pragma unroll 1
  for (int s = 0; s < 3; ++s) {
    stage_species_l(p.W1[s], p.b1[s], p.W2[s], p.b2[s],
                    sW1v, sB2v, sBfv, t, lane, lq, lr, wave);
    const float* X = p.x[s];
    const int rowoff = wave * 16 + lr;
#pragma unroll 1
    for (int qq = 0; qq < 2; ++qq) {
      const int gq = qq * 4;
      float x0[4], x1[4], x2[4];
#pragma unroll
      for (int a = 0; a < 4; ++a) {
        const float* xp = X + ((atom0 + gq + a) * 64 + rowoff) * 3;
        x0[a] = xp[0]; x1[a] = xp[1]; x2[a] = xp[2];
      }
      float mr[4][4];
#pragma unroll
      for (int a = 0; a < 4; ++a) {
        const unsigned mw = (unsigned)__ballot((x0[a] + x1[a] + x2[a]) != 0.0f);
#pragma unroll
        for (int j = 0; j < 4; ++j)
          mr[a][j] = ((mw >> (lq * 4 + j)) & 1u) ? INVS : 0.0f;
      }
      short8 af[4][4];
#pragma unroll
      for (int kb = 0; kb < 4; ++kb) {
        const f32x4* wrow = sW1v + kb * 36 + lq * 9;
        unsigned u[4][4];
#pragma unroll
        for (int e2 = 0; e2 < 4; ++e2) {
          f32x4 wA = wrow[2 * e2], wB = wrow[2 * e2 + 1];
#pragma unroll
          for (int a = 0; a < 4; ++a) {
            float zA = celu_s(fmaf(x0[a], wA.x, fmaf(x1[a], wA.y, fmaf(x2[a], wA.z, wA.w))));
            float zB = celu_s(fmaf(x0[a], wB.x, fmaf(x1[a], wB.y, fmaf(x2[a], wB.z, wB.w))));
            u[a][e2] = cvtpk(zA, zB);
          }
        }
#pragma unroll
        for (int a = 0; a < 4; ++a)
          af[a][kb] = pack4(u[a][0], u[a][1], u[a][2], u[a][3]);
      }
#pragma unroll
      for (int ob = 0; ob < 8; ++ob) {
        const short8* fb = sBfv + (ob * 4) * 64 + lane;
        const float bv = sB2v[ob * 16 + lr];
        f32x4 ac[4];
#pragma unroll
        for (int a = 0; a < 4; ++a) ac[a] = {bv, bv, bv, bv};
#pragma unroll
        for (int kb = 0; kb < 4; ++kb) {
          short8 fr = fb[kb * 64];
#pragma unroll
          for (int a = 0; a < 4; ++a)
            ac[a] = __builtin_amdgcn_mfma_f32_16x16x32_bf16(af[a][kb], fr, ac[a], 0, 0, 0);
        }
        const int col = ob * 16 + lr;
#pragma unroll
        for (int a = 0; a < 4; ++a) {
          float pa = 0.0f;
#pragma unroll
          for (int j = 0; j < 4; ++j)
            pa = fmaf(celu_s(ac[a][j]), mr[a][j], pa);
          pa += __shfl_xor(pa, 16, 64);
          pa += __shfl_xor(pa, 32, 64);
          if (lane < 16) atomicAdd(&sAtm[(gq + a) * 128 + col], pa);
        }
      }
    }
  }
  {
    stage_species_l(p.W1[3], p.b1[3], p.W2[3], p.b2[3],
                    sW1v, sB2v, sBfv, t, lane, lq, lr, wave);
    const int ri = min(atom0 + lr, NATOMS - 1);
    const float* xp = p.x[3] + ri * 3;
    const float x0 = xp[0], x1 = xp[1], x2 = xp[2];
    const unsigned mbi = (unsigned)__ballot((x0 + x1 + x2) != 0.0f);
    short8 af[4];
#pragma unroll
    for (int kb = 0; kb < 4; ++kb) {
      const f32x4* wrow = sW1v + kb * 36 + lq * 9;
      unsigned u[4];
#pragma unroll
      for (int e2 = 0; e2 < 4; ++e2) {
        f32x4 wA = wrow[2 * e2], wB = wrow[2 * e2 + 1];
        float cA = celu_s(fmaf(x0, wA.x, fmaf(x1, wA.y, fmaf(x2, wA.z, wA.w))));
        float cB = celu_s(fmaf(x0, wB.x, fmaf(x1, wB.y, fmaf(x2, wB.z, wB.w))));
        u[e2] = cvtpk(cA, cB);
      }
      af[kb] = pack4(u[0], u[1], u[2], u[3]);
    }
#pragma unroll
    for (int oo = 0; oo < 2; ++oo) {
      const int ob = wave * 2 + oo;
      const int col = ob * 16 + lr;
      const float bv = sB2v[col];
      const short8* fb = sBfv + (ob * 4) * 64 + lane;
      f32x4 a = {bv, bv, bv, bv};
#pragma unroll
      for (int kb = 0; kb < 4; ++kb)
        a = __builtin_amdgcn_mfma_f32_16x16x32_bf16(af[kb], fb[kb * 64], a, 0, 0, 0);
#pragma unroll
      for (int j = 0; j < 4; ++j) {
        const int g = lq * 4 + j;
        if (g < G_) {
          float m = ((mbi >> g) & 1u) ? INVS : 0.0f;
          sAtm[g * 128 + col] += celu_s(a[j]) * m;
        }
      }
    }
    if (wave == 0 && t < G_) sIm[t] = (float)((mbi >> t) & 1u);
    __syncthreads();
  }
  {
    const int g = t >> 4, u = t & 15;
    const bool act = (g < G_);
    if (act) {
      const f32x4* atm4 = (const f32x4*)(sAtm + g * 128);
#pragma unroll
      for (int rep = 0; rep < 4; ++rep) {
        const int o = rep * 16 + u;
        const f32x4* w4 = (const f32x4*)(p.HW[0] + o * 128);
        float z = p.Hb[0][o];
#pragma unroll 8
        for (int c = 0; c < 32; ++c) {
          f32x4 a = atm4[c], w = w4[c];
          z = fmaf(a.x, w.x, fmaf(a.y, w.y, fmaf(a.z, w.z, fmaf(a.w, w.w, z))));
        }
        sH1[g * 64 + o] = celu01(z);
      }
    }
    __syncthreads();
    if (act) {
      const f32x4* h14 = (const f32x4*)(sH1 + g * 64);
#pragma unroll
      for (int rep = 0; rep < 2; ++rep) {
        const int o = rep * 16 + u;
        const f32x4* w4 = (const f32x4*)(p.HW[1] + o * 64);
        float z = p.Hb[1][o];
#pragma unroll
        for (int c = 0; c < 16; ++c) {
          f32x4 a = h14[c], w = w4[c];
          z = fmaf(a.x, w.x, fmaf(a.y, w.y, fmaf(a.z, w.z, fmaf(a.w, w.w, z))));
        }
        sH2[g * 32 + o] = celu01(z);
      }
    }
    __syncthreads();
    if (act) {
      const f32x4* h24 = (const f32x4*)(sH2 + g * 32);
      const f32x4* w4 = (const f32x4*)(p.HW[2] + u * 32);
      float z = p.Hb[2][u];
#pragma unroll
      for (int c = 0; c < 8; ++c) {
        f32x4 a = h24[c], w = w4[c];
        z = fmaf(a.x, w.x, fmaf(a.y, w.y, fmaf(a.z, w.z, fmaf(a.w, w.w, z))));
      }
      sH3[g * 16 + u] = celu01(z);
    }
    __syncthreads();
    if (act && u == 0) {
      const f32x4* h34 = (const f32x4*)(sH3 + g * 16);
      const f32x4* w4 = (const f32x4*)p.HW[3];
      float z = p.Hb[3][0];
#pragma unroll
      for (int c = 0; c < 4; ++c) {
        f32x4 a = h34[c], w = w4[c];
        z = fmaf(a.x, w.x, fmaf(a.y, w.y, fmaf(a.z, w.z, fmaf(a.w, w.w, z))));
      }
      p.out[atom0 + g] = z * sIm[g];
    }
  }
}

extern "C" void kernel_launch(void* const* d_in, const int* in_sizes, int n_in,
                              void* d_out, int out_size, void* d_ws, size_t ws_size,
                              hipStream_t stream) {
  (void)in_sizes; (void)n_in; (void)out_size;
  DartParams p;
  // dict order: ai aj ak al | Wi1 bi1 Wi2 bi2 | Wj1 bj1 Wj2 bj2 | Wk1 bk1 Wk2 bk2
  //             | Wl1 bl1 Wl2 bl2 | W1 b1 W2 b2 W3 b3 W4 b4
  p.x[0] = (const float*)d_in[1];   // aj
  p.x[1] = (const float*)d_in[2];   // ak
  p.x[2] = (const float*)d_in[3];   // al
  p.x[3] = (const float*)d_in[0];   // ai
  p.W1[0] = (const float*)d_in[8];  p.b1[0] = (const float*)d_in[9];
  p.W2[0] = (const float*)d_in[10]; p.b2[0] = (const float*)d_in[11];
  p.W1[1] = (const float*)d_in[12]; p.b1[1] = (const float*)d_in[13];
  p.W2[1] = (const float*)d_in[14]; p.b2[1] = (const float*)d_in[15];
  p.W1[2] = (const float*)d_in[16]; p.b1[2] = (const float*)d_in[17];
  p.W2[2] = (const float*)d_in[18]; p.b2[2] = (const float*)d_in[19];
  p.W1[3] = (const float*)d_in[4];  p.b1[3] = (const float*)d_in[5];
  p.W2[3] = (const float*)d_in[6];  p.b2[3] = (const float*)d_in[7];
  p.HW[0] = (const float*)d_in[20]; p.Hb[0] = (const float*)d_in[21];
  p.HW[1] = (const float*)d_in[22]; p.Hb[1] = (const float*)d_in[23];
  p.HW[2] = (const float*)d_in[24]; p.Hb[2] = (const float*)d_in[25];
  p.HW[3] = (const float*)d_in[26]; p.Hb[3] = (const float*)d_in[27];
  p.out = (float*)d_out;

  if (ws_size >= (size_t)WS_BF_BYTES) {
    short8* ws = (short8*)d_ws;
    p.gBf = ws;
    dart_prep<<<dim3(4), dim3(256), 0, stream>>>(p.W2[0], p.W2[1], p.W2[2], p.W2[3], ws);
    dart_fused_g<<<dim3(NATOMS / G_), dim3(256), 0, stream>>>(p);
  } else {
    p.gBf = nullptr;
    dart_fused_l<<<dim3(NATOMS / G_), dim3(256), 0, stream>>>(p);
  }
}

// Round 20
// 181.554 us; speedup vs baseline: 1.1844x; 1.1844x over previous
//
#include <hip/hip_runtime.h>

// DART_Net fused kernel, MI355X (gfx950). Round 20.
// B=64, N=128, M=64, LH=LO=128. Output [B*N] fp32.
//
// R20 = R14 (152.2us champion) with G=4 (grid 2048) instead of G=8.
// R19 falsified the LDS-occupancy theory: occupancy stayed 42% at 10.75KB
// LDS because the GRID (1024 blocks = 4/CU) was the cap all along, and the
// global-B-frag path added 165MB HBM (L2 thrashed by streaming x) + 150MB
// spill -> reverted to LDS B-frags. G=4 doubles the grid to 2048 (8
// available blocks/CU vs 4 resident) giving the scheduler swap-in slack to
// close the tail-imbalance gap (measured 40% vs 50% cap). Staging cost
// ~+1us (cheap per block). Everything else R14 verbatim.

typedef __attribute__((ext_vector_type(8))) short short8;   // bf16x8 frag
typedef __attribute__((ext_vector_type(4))) float f32x4;
typedef __attribute__((ext_vector_type(4))) unsigned uint4v;

#define G_ 4
#define NATOMS (64 * 128)
#define SCL   14.42695040888963f     // 10/ln2
#define SCL01 1.442695040888963f     // 0.1 * SCL
#define INVS  0.06931471805599453f   // ln2/10

// LDS layout (bytes):
//   [    0, 32768)  sBf  : bf16 B-frags [ob*4+kb][lane] (16B each)
//                   (after species: sH1 @0 [4*64], sH2 @1024, sH3 @1536)
//   [32768, 35072)  sW1  : f32x4[144] {S*w0,S*w1,S*w2,S*b1}, idx = c+(c>>3)
//   [35072, 35584)  sB2  : float[128]  (S*b2)
//   [35584, 37632)  sAtm : float[4][128]
//   [37632, 37648)  sIm  : float[4]
#define LDS_BYTES 37648

struct DartParams {
  const float* x[4];    // aj, ak, al, ai
  const float* W1[4];
  const float* b1[4];
  const float* W2[4];
  const float* b2[4];
  const float* HW[4];   // 64x128, 32x64, 16x32, 1x16
  const float* Hb[4];
  float* out;
};

__device__ __forceinline__ float celu01(float z) {
  // plain-domain celu (head MLP): med3(z, 0.1*exp(10z)-0.1, 0)
  float t = fmaf(0.1f, __builtin_amdgcn_exp2f(z * SCL), -0.1f);
  return __builtin_amdgcn_fmed3f(z, t, 0.0f);
}

__device__ __forceinline__ float celu_s(float zs) {
  // scaled domain: zs = S*z; returns S*celu(z). 3 VALU ops.
  float t = fmaf(SCL01, __builtin_amdgcn_exp2f(zs), -SCL01);
  return __builtin_amdgcn_fmed3f(zs, t, 0.0f);
}

__device__ __forceinline__ unsigned cvtpk(float a, float b) {
  unsigned r;
  asm("v_cvt_pk_bf16_f32 %0, %1, %2" : "=v"(r) : "v"(a), "v"(b));
  return r;
}
__device__ __forceinline__ short8 pack4(unsigned a, unsigned b, unsigned c, unsigned d) {
  uint4v u = {a, b, c, d};
  return __builtin_bit_cast(short8, u);
}

// Stage one species' weights into LDS: sW1 pre-scaled by S (padded f32x4),
// sB2 = S*b2, and bf16 W2 B-fragments [ob*4+kb][lane] (UNscaled).
__device__ __forceinline__ void stage_species(
    const float* W1g, const float* b1g, const float* W2g, const float* b2g,
    f32x4* sW1v, float* sB2v, short8* sBfv,
    int t, int lane, int lq, int lr, int wave) {
  __syncthreads();
  if (t < 128) {
    const float* w = W1g + t * 3;
    f32x4 v;
    v.x = w[0] * SCL; v.y = w[1] * SCL; v.z = w[2] * SCL; v.w = b1g[t] * SCL;
    sW1v[t + (t >> 3)] = v;
    sB2v[t] = b2g[t] * SCL;
  }
#pragma unroll
  for (int ff = 0; ff < 8; ++ff) {
    const int f  = wave * 8 + ff;
    const int ob = f >> 2, kb = f & 3;
    const f32x4* src = (const f32x4*)(W2g + (ob * 16 + lr) * 128 + kb * 32 + lq * 8);
    f32x4 lo = src[0], hi = src[1];
    sBfv[f * 64 + lane] = pack4(cvtpk(lo.x, lo.y), cvtpk(lo.z, lo.w),
                                cvtpk(hi.x, hi.y), cvtpk(hi.z, hi.w));
  }
  __syncthreads();
}

extern "C" __global__ __launch_bounds__(256, 4)
void dart_fused(DartParams p) {
  __shared__ __align__(16) char lds[LDS_BYTES];
  short8* sBfv = (short8*)lds;
  f32x4*  sW1v = (f32x4*)(lds + 32768);
  float*  sB2v = (float*)(lds + 35072);
  float*  sAtm = (float*)(lds + 35584);   // [4*128]
  float*  sIm  = (float*)(lds + 37632);   // [4]
  float*  sH1  = (float*)lds;             // [4*64]  (after species)
  float*  sH2  = (float*)(lds + 1024);    // [4*32]
  float*  sH3  = (float*)(lds + 1536);    // [4*16]

  const int t    = threadIdx.x;
  const int lane = t & 63;
  const int wave = t >> 6;        // 0..3 -> row block wave*16
  const int lq   = lane >> 4;
  const int lr   = lane & 15;
  const int atom0 = (int)blockIdx.x * G_;

  for (int i = t; i < G_ * 128; i += 256) sAtm[i] = 0.0f;

  // ---------------- species j, k, l ----------------
#pragma unroll 1
  for (int s = 0; s < 3; ++s) {
    stage_species(p.W1[s], p.b1[s], p.W2[s], p.b2[s],
                  sW1v, sB2v, sBfv, t, lane, lq, lr, wave);

    const float* X = p.x[s];
    const int rowoff = wave * 16 + lr;

    // single quad (G_=4): atoms atom0..atom0+3
    {
      const int gq = 0;
      float x0[4], x1[4], x2[4];
#pragma unroll
      for (int a = 0; a < 4; ++a) {
        const float* xp = X + ((atom0 + gq + a) * 64 + rowoff) * 3;
        x0[a] = xp[0]; x1[a] = xp[1]; x2[a] = xp[2];
      }
      float mr[4][4];
#pragma unroll
      for (int a = 0; a < 4; ++a) {
        const unsigned mw = (unsigned)__ballot((x0[a] + x1[a] + x2[a]) != 0.0f);
#pragma unroll
        for (int j = 0; j < 4; ++j)
          mr[a][j] = ((mw >> (lq * 4 + j)) & 1u) ? INVS : 0.0f;
      }

      // ---- layer 1 (scaled) + celu_s + cvt_pk pack, 4 atoms ----
      short8 af[4][4];   // [atom][kb]
#pragma unroll
      for (int kb = 0; kb < 4; ++kb) {
        const f32x4* wrow = sW1v + kb * 36 + lq * 9;   // padded index
        unsigned u[4][4];
#pragma unroll
        for (int e2 = 0; e2 < 4; ++e2) {
          f32x4 wA = wrow[2 * e2], wB = wrow[2 * e2 + 1];
#pragma unroll
          for (int a = 0; a < 4; ++a) {
            float zA = celu_s(fmaf(x0[a], wA.x, fmaf(x1[a], wA.y, fmaf(x2[a], wA.z, wA.w))));
            float zB = celu_s(fmaf(x0[a], wB.x, fmaf(x1[a], wB.y, fmaf(x2[a], wB.z, wB.w))));
            u[a][e2] = cvtpk(zA, zB);
          }
        }
#pragma unroll
        for (int a = 0; a < 4; ++a)
          af[a][kb] = pack4(u[a][0], u[a][1], u[a][2], u[a][3]);
      }

      // ---- per-ob: one B-frag read feeds 4 atoms; 16 MFMAs; epilogue ----
#pragma unroll
      for (int ob = 0; ob < 8; ++ob) {
        const short8* fb = sBfv + (ob * 4) * 64 + lane;
        const float bv = sB2v[ob * 16 + lr];   // S*b2 -> acc is z2'
        f32x4 ac[4];
#pragma unroll
        for (int a = 0; a < 4; ++a) ac[a] = {bv, bv, bv, bv};
#pragma unroll
        for (int kb = 0; kb < 4; ++kb) {
          short8 fr = fb[kb * 64];
#pragma unroll
          for (int a = 0; a < 4; ++a)
            ac[a] = __builtin_amdgcn_mfma_f32_16x16x32_bf16(af[a][kb], fr, ac[a], 0, 0, 0);
        }
        const int col = ob * 16 + lr;
#pragma unroll
        for (int a = 0; a < 4; ++a) {
          float pa = 0.0f;
#pragma unroll
          for (int j = 0; j < 4; ++j)
            pa = fmaf(celu_s(ac[a][j]), mr[a][j], pa);   // mr carries 1/S
          pa += __shfl_xor(pa, 16, 64);
          pa += __shfl_xor(pa, 32, 64);
          if (lane < 16) atomicAdd(&sAtm[(gq + a) * 128 + col], pa);
        }
      }
    }
  }

  // ---------------- species i: one 16-row GEMM (rows = atoms) ----------------
  {
    stage_species(p.W1[3], p.b1[3], p.W2[3], p.b2[3],
                  sW1v, sB2v, sBfv, t, lane, lq, lr, wave);
    // (leading barrier also guarantees all j/k/l sAtm atomics complete)

    const int ri = min(atom0 + lr, NATOMS - 1);
    const float* xp = p.x[3] + ri * 3;
    const float x0 = xp[0], x1 = xp[1], x2 = xp[2];
    const unsigned mbi = (unsigned)__ballot((x0 + x1 + x2) != 0.0f);

    short8 af[4];
#pragma unroll
    for (int kb = 0; kb < 4; ++kb) {
      const f32x4* wrow = sW1v + kb * 36 + lq * 9;
      unsigned u[4];
#pragma unroll
      for (int e2 = 0; e2 < 4; ++e2) {
        f32x4 wA = wrow[2 * e2], wB = wrow[2 * e2 + 1];
        float cA = celu_s(fmaf(x0, wA.x, fmaf(x1, wA.y, fmaf(x2, wA.z, wA.w))));
        float cB = celu_s(fmaf(x0, wB.x, fmaf(x1, wB.y, fmaf(x2, wB.z, wB.w))));
        u[e2] = cvtpk(cA, cB);
      }
      af[kb] = pack4(u[0], u[1], u[2], u[3]);
    }
    // each wave handles 2 output blocks: ob = wave*2, wave*2+1 (disjoint cols)
#pragma unroll
    for (int oo = 0; oo < 2; ++oo) {
      const int ob = wave * 2 + oo;
      const int col = ob * 16 + lr;
      const float bv = sB2v[col];
      const short8* fb = sBfv + (ob * 4) * 64 + lane;
      f32x4 a = {bv, bv, bv, bv};
#pragma unroll
      for (int kb = 0; kb < 4; ++kb)
        a = __builtin_amdgcn_mfma_f32_16x16x32_bf16(af[kb], fb[kb * 64], a, 0, 0, 0);
#pragma unroll
      for (int j = 0; j < 4; ++j) {
        const int g = lq * 4 + j;
        if (g < G_) {
          float m = ((mbi >> g) & 1u) ? INVS : 0.0f;
          sAtm[g * 128 + col] += celu_s(a[j]) * m;
        }
      }
    }
    if (wave == 0 && t < G_) sIm[t] = (float)((mbi >> t) & 1u);
    __syncthreads();   // sAtm final; sBf reads done (head reuses that space)
  }

  // ---------------- head MLP: 128 -> 64 -> 32 -> 16 -> 1 (plain domain) ----
  {
    const int g = t >> 4, u = t & 15;
    const bool act = (g < G_);
    if (act) {
      const f32x4* atm4 = (const f32x4*)(sAtm + g * 128);
#pragma unroll
      for (int rep = 0; rep < 4; ++rep) {
        const int o = rep * 16 + u;
        const f32x4* w4 = (const f32x4*)(p.HW[0] + o * 128);
        float z = p.Hb[0][o];
#pragma unroll 8
        for (int c = 0; c < 32; ++c) {
          f32x4 a = atm4[c], w = w4[c];
          z = fmaf(a.x, w.x, fmaf(a.y, w.y, fmaf(a.z, w.z, fmaf(a.w, w.w, z))));
        }
        sH1[g * 64 + o] = celu01(z);
      }
    }
    __syncthreads();
    if (act) {
      const f32x4* h14 = (const f32x4*)(sH1 + g * 64);
#pragma unroll
      for (int rep = 0; rep < 2; ++rep) {
        const int o = rep * 16 + u;
        const f32x4* w4 = (const f32x4*)(p.HW[1] + o * 64);
        float z = p.Hb[1][o];
#pragma unroll
        for (int c = 0; c < 16; ++c) {
          f32x4 a = h14[c], w = w4[c];
          z = fmaf(a.x, w.x, fmaf(a.y, w.y, fmaf(a.z, w.z, fmaf(a.w, w.w, z))));
        }
        sH2[g * 32 + o] = celu01(z);
      }
    }
    __syncthreads();
    if (act) {
      const f32x4* h24 = (const f32x4*)(sH2 + g * 32);
      const f32x4* w4 = (const f32x4*)(p.HW[2] + u * 32);
      float z = p.Hb[2][u];
#pragma unroll
      for (int c = 0; c < 8; ++c) {
        f32x4 a = h24[c], w = w4[c];
        z = fmaf(a.x, w.x, fmaf(a.y, w.y, fmaf(a.z, w.z, fmaf(a.w, w.w, z))));
      }
      sH3[g * 16 + u] = celu01(z);
    }
    __syncthreads();
    if (act && u == 0) {
      const f32x4* h34 = (const f32x4*)(sH3 + g * 16);
      const f32x4* w4 = (const f32x4*)p.HW[3];
      float z = p.Hb[3][0];
#pragma unroll
      for (int c = 0; c < 4; ++c) {
        f32x4 a = h34[c], w = w4[c];
        z = fmaf(a.x, w.x, fmaf(a.y, w.y, fmaf(a.z, w.z, fmaf(a.w, w.w, z))));
      }
      p.out[atom0 + g] = z * sIm[g];
    }
  }
}

extern "C" void kernel_launch(void* const* d_in, const int* in_sizes, int n_in,
                              void* d_out, int out_size, void* d_ws, size_t ws_size,
                              hipStream_t stream) {
  (void)in_sizes; (void)n_in; (void)out_size; (void)d_ws; (void)ws_size;
  DartParams p;
  // dict order: ai aj ak al | Wi1 bi1 Wi2 bi2 | Wj1 bj1 Wj2 bj2 | Wk1 bk1 Wk2 bk2
  //             | Wl1 bl1 Wl2 bl2 | W1 b1 W2 b2 W3 b3 W4 b4
  p.x[0] = (const float*)d_in[1];   // aj
  p.x[1] = (const float*)d_in[2];   // ak
  p.x[2] = (const float*)d_in[3];   // al
  p.x[3] = (const float*)d_in[0];   // ai
  p.W1[0] = (const float*)d_in[8];  p.b1[0] = (const float*)d_in[9];
  p.W2[0] = (const float*)d_in[10]; p.b2[0] = (const float*)d_in[11];
  p.W1[1] = (const float*)d_in[12]; p.b1[1] = (const float*)d_in[13];
  p.W2[1] = (const float*)d_in[14]; p.b2[1] = (const float*)d_in[15];
  p.W1[2] = (const float*)d_in[16]; p.b1[2] = (const float*)d_in[17];
  p.W2[2] = (const float*)d_in[18]; p.b2[2] = (const float*)d_in[19];
  p.W1[3] = (const float*)d_in[4];  p.b1[3] = (const float*)d_in[5];
  p.W2[3] = (const float*)d_in[6];  p.b2[3] = (const float*)d_in[7];
  p.HW[0] = (const float*)d_in[20]; p.Hb[0] = (const float*)d_in[21];
  p.HW[1] = (const float*)d_in[22]; p.Hb[1] = (const float*)d_in[23];
  p.HW[2] = (const float*)d_in[24]; p.Hb[2] = (const float*)d_in[25];
  p.HW[3] = (const float*)d_in[26]; p.Hb[3] = (const float*)d_in[27];
  p.out = (float*)d_out;

  dart_fused<<<dim3(NATOMS / G_), dim3(256), 0, stream>>>(p);
}

// Round 21
// 146.603 us; speedup vs baseline: 1.4667x; 1.2384x over previous
//
#include <hip/hip_runtime.h>

// DART_Net fused kernel, MI355X (gfx950). Round 21.
// B=64, N=128, M=64, LH=LO=128. Output [B*N] fp32.
//
// R21 = R14 (152.2us champion) + prep-kernel W2 image + global_load_lds
// staging. R20 calibrated staging at ~25-30us of the 172us wall (doubling
// stagings cost +29us). The per-block f32->bf16 conversion (256KB f32 loads
// + ~64 cvtpk/thread + ds_writes, x4 species) is replaced by:
//   - dart_prep (4 blocks, once per call): W2 f32 -> bf16 MFMA-frag image
//     in d_ws (128 KB). Identical cvtpk values -> bit-identical result.
//   - stage: 8x __builtin_amdgcn_global_load_lds(width=16) per thread per
//     species. LDS dest = wave-uniform frag base (HW adds lane*16; our
//     [f][lane] layout is linear-contiguous); global src per-lane.
// Unlike R19 (hot-loop global reads -> L2 thrash), the image is read ONCE
// per block-species into LDS; the hot loop is R14 verbatim.
// Fallback (ws too small): R14 kernel verbatim.

typedef __attribute__((ext_vector_type(8))) short short8;   // bf16x8 frag
typedef __attribute__((ext_vector_type(4))) float f32x4;
typedef __attribute__((ext_vector_type(4))) unsigned uint4v;

#define G_ 8
#define NATOMS (64 * 128)
#define SCL   14.42695040888963f     // 10/ln2
#define SCL01 1.442695040888963f     // 0.1 * SCL
#define INVS  0.06931471805599453f   // ln2/10
#define WS_BF_BYTES (4 * 32 * 64 * 16)   // 4 species x 32 frags x 64 lanes x 16B

// LDS layout (bytes):
//   [    0, 32768)  sBf  : bf16 B-frags [ob*4+kb][lane] (16B each)
//                   (after species: sH1 @0 [8*64], sH2 @2048, sH3 @3072)
//   [32768, 35072)  sW1  : f32x4[144] {S*w0,S*w1,S*w2,S*b1}, idx = c+(c>>3)
//   [35072, 35584)  sB2  : float[128]  (S*b2)
//   [35584, 39680)  sAtm : float[8][128]
//   [39680, 39712)  sIm  : float[8]
#define LDS_BYTES 39712

struct DartParams {
  const float* x[4];    // aj, ak, al, ai
  const float* W1[4];
  const float* b1[4];
  const float* W2[4];
  const float* b2[4];
  const float* HW[4];   // 64x128, 32x64, 16x32, 1x16
  const float* Hb[4];
  const short8* gBf;    // [4][32][64] bf16 B-frag image (prep), or null
  float* out;
};

__device__ __forceinline__ float celu01(float z) {
  // plain-domain celu (head MLP): med3(z, 0.1*exp(10z)-0.1, 0)
  float t = fmaf(0.1f, __builtin_amdgcn_exp2f(z * SCL), -0.1f);
  return __builtin_amdgcn_fmed3f(z, t, 0.0f);
}
__device__ __forceinline__ float celu_s(float zs) {
  // scaled domain: zs = S*z; returns S*celu(z). 3 VALU ops.
  float t = fmaf(SCL01, __builtin_amdgcn_exp2f(zs), -SCL01);
  return __builtin_amdgcn_fmed3f(zs, t, 0.0f);
}
__device__ __forceinline__ unsigned cvtpk(float a, float b) {
  unsigned r;
  asm("v_cvt_pk_bf16_f32 %0, %1, %2" : "=v"(r) : "v"(a), "v"(b));
  return r;
}
__device__ __forceinline__ short8 pack4(unsigned a, unsigned b, unsigned c, unsigned d) {
  uint4v u = {a, b, c, d};
  return __builtin_bit_cast(short8, u);
}

// ---------------- prep: W2 f32 -> bf16 MFMA B-frag image in ws ----------------
extern "C" __global__ __launch_bounds__(256)
void dart_prep(const float* W2j, const float* W2k, const float* W2l,
               const float* W2i, short8* ws) {
  const int s = (int)blockIdx.x;            // 0..3 species (j,k,l,i)
  const float* W2 = (s == 0) ? W2j : (s == 1) ? W2k : (s == 2) ? W2l : W2i;
  const int t = threadIdx.x;
  const int lane = t & 63, wave = t >> 6;
  const int lq = lane >> 4, lr = lane & 15;
#pragma unroll
  for (int ff = 0; ff < 8; ++ff) {
    const int f  = wave * 8 + ff;
    const int ob = f >> 2, kb = f & 3;
    const f32x4* src = (const f32x4*)(W2 + (ob * 16 + lr) * 128 + kb * 32 + lq * 8);
    f32x4 lo = src[0], hi = src[1];
    ws[(s * 32 + f) * 64 + lane] = pack4(cvtpk(lo.x, lo.y), cvtpk(lo.z, lo.w),
                                         cvtpk(hi.x, hi.y), cvtpk(hi.z, hi.w));
  }
}

// ---- staging: W1/b2 as before; sBf via global_load_lds from prep image ----
__device__ __forceinline__ void stage_species_g(
    const float* W1g, const float* b1g, const float* b2g, const short8* gBfs,
    f32x4* sW1v, float* sB2v, short8* sBfv,
    int t, int lane, int wave) {
  __syncthreads();
  if (t < 128) {
    const float* w = W1g + t * 3;
    f32x4 v;
    v.x = w[0] * SCL; v.y = w[1] * SCL; v.z = w[2] * SCL; v.w = b1g[t] * SCL;
    sW1v[t + (t >> 3)] = v;
    sB2v[t] = b2g[t] * SCL;
  }
#pragma unroll
  for (int ff = 0; ff < 8; ++ff) {
    const int f = wave * 8 + ff;
    // global src is per-lane; LDS dest is wave-uniform base (HW adds lane*16)
    const unsigned* src = (const unsigned*)(gBfs + f * 64 + lane);
    unsigned* dst = (unsigned*)(sBfv + f * 64);
    __builtin_amdgcn_global_load_lds(
        (const __attribute__((address_space(1))) unsigned*)src,
        (__attribute__((address_space(3))) unsigned*)dst, 16, 0, 0);
  }
  __syncthreads();   // compiler drains vmcnt before the barrier
}

// fallback staging (R14 verbatim): converts f32 W2 in-block
__device__ __forceinline__ void stage_species_l(
    const float* W1g, const float* b1g, const float* W2g, const float* b2g,
    f32x4* sW1v, float* sB2v, short8* sBfv,
    int t, int lane, int lq, int lr, int wave) {
  __syncthreads();
  if (t < 128) {
    const float* w = W1g + t * 3;
    f32x4 v;
    v.x = w[0] * SCL; v.y = w[1] * SCL; v.z = w[2] * SCL; v.w = b1g[t] * SCL;
    sW1v[t + (t >> 3)] = v;
    sB2v[t] = b2g[t] * SCL;
  }
#pragma unroll
  for (int ff = 0; ff < 8; ++ff) {
    const int f  = wave * 8 + ff;
    const int ob = f >> 2, kb = f & 3;
    const f32x4* src = (const f32x4*)(W2g + (ob * 16 + lr) * 128 + kb * 32 + lq * 8);
    f32x4 lo = src[0], hi = src[1];
    sBfv[f * 64 + lane] = pack4(cvtpk(lo.x, lo.y), cvtpk(lo.z, lo.w),
                                cvtpk(hi.x, hi.y), cvtpk(hi.z, hi.w));
  }
  __syncthreads();
}

// ---------------- main body (shared by both kernels) ----------------
template <bool USE_G>
__device__ __forceinline__ void dart_body(const DartParams& p) {
  __shared__ __align__(16) char lds[LDS_BYTES];
  short8* sBfv = (short8*)lds;
  f32x4*  sW1v = (f32x4*)(lds + 32768);
  float*  sB2v = (float*)(lds + 35072);
  float*  sAtm = (float*)(lds + 35584);   // [8*128]
  float*  sIm  = (float*)(lds + 39680);   // [8]
  float*  sH1  = (float*)lds;             // [8*64]  (after species)
  float*  sH2  = (float*)(lds + 2048);    // [8*32]
  float*  sH3  = (float*)(lds + 3072);    // [8*16]

  const int t    = threadIdx.x;
  const int lane = t & 63;
  const int wave = t >> 6;        // 0..3 -> row block wave*16
  const int lq   = lane >> 4;
  const int lr   = lane & 15;
  const int atom0 = (int)blockIdx.x * G_;

  for (int i = t; i < G_ * 128; i += 256) sAtm[i] = 0.0f;

  // ---------------- species j, k, l ----------------
#pragma unroll 1
  for (int s = 0; s < 3; ++s) {
    if (USE_G)
      stage_species_g(p.W1[s], p.b1[s], p.b2[s], p.gBf + s * 32 * 64,
                      sW1v, sB2v, sBfv, t, lane, wave);
    else
      stage_species_l(p.W1[s], p.b1[s], p.W2[s], p.b2[s],
                      sW1v, sB2v, sBfv, t, lane, lq, lr, wave);

    const float* X = p.x[s];
    const int rowoff = wave * 16 + lr;

#pragma unroll 1
    for (int qq = 0; qq < 2; ++qq) {
      const int gq = qq * 4;
      float x0[4], x1[4], x2[4];
#pragma unroll
      for (int a = 0; a < 4; ++a) {
        const float* xp = X + ((atom0 + gq + a) * 64 + rowoff) * 3;
        x0[a] = xp[0]; x1[a] = xp[1]; x2[a] = xp[2];
      }
      float mr[4][4];
#pragma unroll
      for (int a = 0; a < 4; ++a) {
        const unsigned mw = (unsigned)__ballot((x0[a] + x1[a] + x2[a]) != 0.0f);
#pragma unroll
        for (int j = 0; j < 4; ++j)
          mr[a][j] = ((mw >> (lq * 4 + j)) & 1u) ? INVS : 0.0f;
      }

      // ---- layer 1 (scaled) + celu_s + cvt_pk pack, 4 atoms ----
      short8 af[4][4];   // [atom][kb]
#pragma unroll
      for (int kb = 0; kb < 4; ++kb) {
        const f32x4* wrow = sW1v + kb * 36 + lq * 9;   // padded index
        unsigned u[4][4];
#pragma unroll
        for (int e2 = 0; e2 < 4; ++e2) {
          f32x4 wA = wrow[2 * e2], wB = wrow[2 * e2 + 1];
#pragma unroll
          for (int a = 0; a < 4; ++a) {
            float zA = celu_s(fmaf(x0[a], wA.x, fmaf(x1[a], wA.y, fmaf(x2[a], wA.z, wA.w))));
            float zB = celu_s(fmaf(x0[a], wB.x, fmaf(x1[a], wB.y, fmaf(x2[a], wB.z, wB.w))));
            u[a][e2] = cvtpk(zA, zB);
          }
        }
#pragma unroll
        for (int a = 0; a < 4; ++a)
          af[a][kb] = pack4(u[a][0], u[a][1], u[a][2], u[a][3]);
      }

      // ---- per-ob: one B-frag read feeds 4 atoms; 16 MFMAs; epilogue ----
#pragma unroll
      for (int ob = 0; ob < 8; ++ob) {
        const short8* fb = sBfv + (ob * 4) * 64 + lane;
        const float bv = sB2v[ob * 16 + lr];   // S*b2 -> acc is z2'
        f32x4 ac[4];
#pragma unroll
        for (int a = 0; a < 4; ++a) ac[a] = {bv, bv, bv, bv};
#pragma unroll
        for (int kb = 0; kb < 4; ++kb) {
          short8 fr = fb[kb * 64];
#pragma unroll
          for (int a = 0; a < 4; ++a)
            ac[a] = __builtin_amdgcn_mfma_f32_16x16x32_bf16(af[a][kb], fr, ac[a], 0, 0, 0);
        }
        const int col = ob * 16 + lr;
#pragma unroll
        for (int a = 0; a < 4; ++a) {
          float pa = 0.0f;
#pragma unroll
          for (int j = 0; j < 4; ++j)
            pa = fmaf(celu_s(ac[a][j]), mr[a][j], pa);   // mr carries 1/S
          pa += __shfl_xor(pa, 16, 64);
          pa += __shfl_xor(pa, 32, 64);
          if (lane < 16) atomicAdd(&sAtm[(gq + a) * 128 + col], pa);
        }
      }
    }
  }

  // ---------------- species i: one 16-row GEMM (rows = atoms) ----------------
  {
    if (USE_G)
      stage_species_g(p.W1[3], p.b1[3], p.b2[3], p.gBf + 3 * 32 * 64,
                      sW1v, sB2v, sBfv, t, lane, wave);
    else
      stage_species_l(p.W1[3], p.b1[3], p.W2[3], p.b2[3],
                      sW1v, sB2v, sBfv, t, lane, lq, lr, wave);

    const int ri = min(atom0 + lr, NATOMS - 1);
    const float* xp = p.x[3] + ri * 3;
    const float x0 = xp[0], x1 = xp[1], x2 = xp[2];
    const unsigned mbi = (unsigned)__ballot((x0 + x1 + x2) != 0.0f);

    short8 af[4];
#pragma unroll
    for (int kb = 0; kb < 4; ++kb) {
      const f32x4* wrow = sW1v + kb * 36 + lq * 9;
      unsigned u[4];
#pragma unroll
      for (int e2 = 0; e2 < 4; ++e2) {
        f32x4 wA = wrow[2 * e2], wB = wrow[2 * e2 + 1];
        float cA = celu_s(fmaf(x0, wA.x, fmaf(x1, wA.y, fmaf(x2, wA.z, wA.w))));
        float cB = celu_s(fmaf(x0, wB.x, fmaf(x1, wB.y, fmaf(x2, wB.z, wB.w))));
        u[e2] = cvtpk(cA, cB);
      }
      af[kb] = pack4(u[0], u[1], u[2], u[3]);
    }
    // each wave handles 2 output blocks: ob = wave*2, wave*2+1 (disjoint cols)
#pragma unroll
    for (int oo = 0; oo < 2; ++oo) {
      const int ob = wave * 2 + oo;
      const int col = ob * 16 + lr;
      const float bv = sB2v[col];
      const short8* fb = sBfv + (ob * 4) * 64 + lane;
      f32x4 a = {bv, bv, bv, bv};
#pragma unroll
      for (int kb = 0; kb < 4; ++kb)
        a = __builtin_amdgcn_mfma_f32_16x16x32_bf16(af[kb], fb[kb * 64], a, 0, 0, 0);
#pragma unroll
      for (int j = 0; j < 4; ++j) {
        const int g = lq * 4 + j;
        if (g < G_) {
          float m = ((mbi >> g) & 1u) ? INVS : 0.0f;
          sAtm[g * 128 + col] += celu_s(a[j]) * m;
        }
      }
    }
    if (wave == 0 && t < G_) sIm[t] = (float)((mbi >> t) & 1u);
    __syncthreads();   // sAtm final; sBf reads done (head reuses that space)
  }

  // ---------------- head MLP: 128 -> 64 -> 32 -> 16 -> 1 (plain domain) ----
  {
    const int g = t >> 4, u = t & 15;
    const bool act = (g < G_);
    if (act) {
      const f32x4* atm4 = (const f32x4*)(sAtm + g * 128);
#pragma unroll
      for (int rep = 0; rep < 4; ++rep) {
        const int o = rep * 16 + u;
        const f32x4* w4 = (const f32x4*)(p.HW[0] + o * 128);
        float z = p.Hb[0][o];
#pragma unroll 8
        for (int c = 0; c < 32; ++c) {
          f32x4 a = atm4[c], w = w4[c];
          z = fmaf(a.x, w.x, fmaf(a.y, w.y, fmaf(a.z, w.z, fmaf(a.w, w.w, z))));
        }
        sH1[g * 64 + o] = celu01(z);
      }
    }
    __syncthreads();
    if (act) {
      const f32x4* h14 = (const f32x4*)(sH1 + g * 64);
#pragma unroll
      for (int rep = 0; rep < 2; ++rep) {
        const int o = rep * 16 + u;
        const f32x4* w4 = (const f32x4*)(p.HW[1] + o * 64);
        float z = p.Hb[1][o];
#pragma unroll
        for (int c = 0; c < 16; ++c) {
          f32x4 a = h14[c], w = w4[c];
          z = fmaf(a.x, w.x, fmaf(a.y, w.y, fmaf(a.z, w.z, fmaf(a.w, w.w, z))));
        }
        sH2[g * 32 + o] = celu01(z);
      }
    }
    __syncthreads();
    if (act) {
      const f32x4* h24 = (const f32x4*)(sH2 + g * 32);
      const f32x4* w4 = (const f32x4*)(p.HW[2] + u * 32);
      float z = p.Hb[2][u];
#pragma unroll
      for (int c = 0; c < 8; ++c) {
        f32x4 a = h24[c], w = w4[c];
        z = fmaf(a.x, w.x, fmaf(a.y, w.y, fmaf(a.z, w.z, fmaf(a.w, w.w, z))));
      }
      sH3[g * 16 + u] = celu01(z);
    }
    __syncthreads();
    if (act && u == 0) {
      const f32x4* h34 = (const f32x4*)(sH3 + g * 16);
      const f32x4* w4 = (const f32x4*)p.HW[3];
      float z = p.Hb[3][0];
#pragma unroll
      for (int c = 0; c < 4; ++c) {
        f32x4 a = h34[c], w = w4[c];
        z = fmaf(a.x, w.x, fmaf(a.y, w.y, fmaf(a.z, w.z, fmaf(a.w, w.w, z))));
      }
      p.out[atom0 + g] = z * sIm[g];
    }
  }
}

extern "C" __global__ __launch_bounds__(256, 4)
void dart_fused_g(DartParams p) { dart_body<true>(p); }

extern "C" __global__ __launch_bounds__(256, 4)
void dart_fused_l(DartParams p) { dart_body<false>(p); }

extern "C" void kernel_launch(void* const* d_in, const int* in_sizes, int n_in,
                              void* d_out, int out_size, void* d_ws, size_t ws_size,
                              hipStream_t stream) {
  (void)in_sizes; (void)n_in; (void)out_size;
  DartParams p;
  // dict order: ai aj ak al | Wi1 bi1 Wi2 bi2 | Wj1 bj1 Wj2 bj2 | Wk1 bk1 Wk2 bk2
  //             | Wl1 bl1 Wl2 bl2 | W1 b1 W2 b2 W3 b3 W4 b4
  p.x[0] = (const float*)d_in[1];   // aj
  p.x[1] = (const float*)d_in[2];   // ak
  p.x[2] = (const float*)d_in[3];   // al
  p.x[3] = (const float*)d_in[0];   // ai
  p.W1[0] = (const float*)d_in[8];  p.b1[0] = (const float*)d_in[9];
  p.W2[0] = (const float*)d_in[10]; p.b2[0] = (const float*)d_in[11];
  p.W1[1] = (const float*)d_in[12]; p.b1[1] = (const float*)d_in[13];
  p.W2[1] = (const float*)d_in[14]; p.b2[1] = (const float*)d_in[15];
  p.W1[2] = (const float*)d_in[16]; p.b1[2] = (const float*)d_in[17];
  p.W2[2] = (const float*)d_in[18]; p.b2[2] = (const float*)d_in[19];
  p.W1[3] = (const float*)d_in[4];  p.b1[3] = (const float*)d_in[5];
  p.W2[3] = (const float*)d_in[6];  p.b2[3] = (const float*)d_in[7];
  p.HW[0] = (const float*)d_in[20]; p.Hb[0] = (const float*)d_in[21];
  p.HW[1] = (const float*)d_in[22]; p.Hb[1] = (const float*)d_in[23];
  p.HW[2] = (const float*)d_in[24]; p.Hb[2] = (const float*)d_in[25];
  p.HW[3] = (const float*)d_in[26]; p.Hb[3] = (const float*)d_in[27];
  p.out = (float*)d_out;

  if (ws_size >= (size_t)WS_BF_BYTES) {
    short8* ws = (short8*)d_ws;
    p.gBf = ws;
    dart_prep<<<dim3(4), dim3(256), 0, stream>>>(p.W2[0], p.W2[1], p.W2[2], p.W2[3], ws);
    dart_fused_g<<<dim3(NATOMS / G_), dim3(256), 0, stream>>>(p);
  } else {
    p.gBf = nullptr;
    dart_fused_l<<<dim3(NATOMS / G_), dim3(256), 0, stream>>>(p);
  }
}